// Round 4
// baseline (310.488 us; speedup 1.0000x reference)
//
#include <hip/hip_runtime.h>
#include <hip/hip_bf16.h>

typedef short bf16x8 __attribute__((ext_vector_type(8)));
typedef float f32x4  __attribute__((ext_vector_type(4)));

#define H_NODE 64
#define H_EDGE 128
#define IN_DIM 256
#define WAVES  8
#define BLOCK  512
#define GRID   256
#define LN_EPS 1e-5f

// Static LDS layout (byte offsets), 128 KiB (1 block/CU):
//   [0,      65536): W1^T bf16: addr = col*512 + ((k*2) ^ ((col&7)<<4)),  col in [0,128), k in [0,256)
//   [65536,  98304): W2^T bf16: addr = 65536 + col*256 + ((k*2) ^ ((col&7)<<4)), k in [0,128)
//   [98304, 131072): per-wave transpose tile (16 rows x 128 bf16, 4KB x 8 waves) -- h only now
//
// Round-4 changes on top of the 262us round-3 structure:
//  (a) per-wave phase stagger (one-time s_sleep skew ~1.5k cyc * wid): the 8
//      waves leave the weight-staging barrier aligned and their LDS-heavy
//      phases collide on the single LDS pipe; skewing them interleaves LDS
//      phases with other waves' VMEM-wait phases.
//  (b) w LDS round-trip eliminated: LN output is stored DIRECTLY from the
//      MFMA C-layout (32 dword stores, each covering 4 full 64B segments),
//      residual re-read in C-layout from L2 (same rows fetched at tile top
//      by this wave -> XCD-local L2 hit). Saves 32 ds_write + 4 b128 reads +
//      one lgkmcnt(0) drain per tile; output now f32-exact (no bf16 roundtrip).
// Spill tripwire: WRITE_SIZE > 600 MB. L2-miss tripwire: FETCH_SIZE +400MB.

static __device__ __forceinline__ short f2bf(float x) {
    __hip_bfloat16 h = __float2bfloat16(x);   // RNE
    return *reinterpret_cast<short*>(&h);
}

static __device__ __forceinline__ float bf2f(short s) {
    union { unsigned int u; float f; } v;
    v.u = ((unsigned int)(unsigned short)s) << 16;
    return v.f;
}

static __device__ __forceinline__ int tswz(int r, int g) {
    return r * 256 + ((g ^ ((r >> 2) << 1)) << 4);
}

static __device__ __forceinline__ bf16x8 cvt8(f32x4 lo, f32x4 hi) {
    bf16x8 f;
    f[0] = f2bf(lo[0]); f[1] = f2bf(lo[1]); f[2] = f2bf(lo[2]); f[3] = f2bf(lo[3]);
    f[4] = f2bf(hi[0]); f[5] = f2bf(hi[1]); f[6] = f2bf(hi[2]); f[7] = f2bf(hi[3]);
    return f;
}

extern "C" __global__ void __launch_bounds__(BLOCK, 2)
edge_update(const float* __restrict__ node,
            const float* __restrict__ edgef,
            const int* __restrict__ ei,          // int32 on device
            const float* __restrict__ W1, const float* __restrict__ b1,
            const float* __restrict__ W2, const float* __restrict__ b2,
            const float* __restrict__ gamma, const float* __restrict__ beta,
            float* __restrict__ out, int E)
{
    __shared__ char lds[131072];
    const int tid = threadIdx.x;

    // ---- stage W1^T (bf16, swizzled) ----
    #pragma unroll 4
    for (int i = 0; i < 64; ++i) {
        int e = tid + i * BLOCK;            // e < 32768; W1 is [k][n], k<256, n<128
        int k = e >> 7, n = e & 127;
        float v = W1[e];
        int addr = n * 512 + ((k * 2) ^ ((n & 7) << 4));
        *(short*)(lds + addr) = f2bf(v);
    }
    // ---- stage W2^T ----
    #pragma unroll 4
    for (int i = 0; i < 32; ++i) {
        int e = tid + i * BLOCK;            // e < 16384; W2 is [k][n], k<128, n<128
        int k = e >> 7, n = e & 127;
        float v = W2[e];
        int addr = 65536 + n * 256 + ((k * 2) ^ ((n & 7) << 4));
        *(short*)(lds + addr) = f2bf(v);
    }
    __syncthreads();

    const int wid   = tid >> 6;
    const int lane  = tid & 63;
    const int lrow  = lane & 15;   // A-frag row / C col / B col
    const int lk8   = lane >> 4;   // k-subchunk 0..3
    const int hbase = 98304 + wid * 4096;

    // ---- (a) one-time phase stagger: ~1.5k cycles per wave id ----
    for (int i = 0; i < wid; ++i) __builtin_amdgcn_s_sleep(24);

    // per-lane column constants (persistent; plenty of regs at 2 waves/SIMD)
    float bias1[8], bias2[8], g8[8], bt8[8];
    #pragma unroll
    for (int n = 0; n < 8; ++n) {
        int c = n * 16 + lrow;
        bias1[n] = b1[c]; bias2[n] = b2[c]; g8[n] = gamma[c]; bt8[n] = beta[c];
    }

    const int ntiles  = (E + 15) >> 4;
    const int wstride = GRID * WAVES;

    int tile = blockIdx.x * WAVES + wid;
    if (tile >= ntiles) return;

    // ---- prologue: indices + staged gather for tile t; indices for t+1 ----
    int rowg = tile * 16 + lrow; if (rowg >= E) rowg = E - 1;
    int sidx = ei[rowg];
    int didx = ei[E + rowg];

    f32x4 Sn0, Sn1, Sn2, Sn3, Sn4, Sn5, Sn6, Sn7;   // node src/dst raw
    f32x4 Se0, Se1, Se2, Se3, Se4, Se5, Se6, Se7;   // edge row raw
    {
        const float* sp = node + (size_t)sidx * H_NODE + lk8 * 8;
        const float* dp = node + (size_t)didx * H_NODE + lk8 * 8;
        const float* ep = edgef + (size_t)rowg * H_EDGE + lk8 * 8;
        Sn0 = *(const f32x4*)(sp);      Sn1 = *(const f32x4*)(sp + 4);
        Sn2 = *(const f32x4*)(sp + 32); Sn3 = *(const f32x4*)(sp + 36);
        Sn4 = *(const f32x4*)(dp);      Sn5 = *(const f32x4*)(dp + 4);
        Sn6 = *(const f32x4*)(dp + 32); Sn7 = *(const f32x4*)(dp + 36);
        Se0 = *(const f32x4*)(ep);      Se1 = *(const f32x4*)(ep + 4);
        Se2 = *(const f32x4*)(ep + 32); Se3 = *(const f32x4*)(ep + 36);
        Se4 = *(const f32x4*)(ep + 64); Se5 = *(const f32x4*)(ep + 68);
        Se6 = *(const f32x4*)(ep + 96); Se7 = *(const f32x4*)(ep + 100);
    }
    int next  = tile + wstride;
    int nrowg = next * 16 + lrow; if (nrowg >= E) nrowg = E - 1;
    int nsidx = ei[nrowg];
    int ndidx = ei[E + nrowg];

    while (tile < ntiles) {
        const int r0 = tile * 16;

        // ---- fold staged gather (issued one full tile ago) into A1 ----
        bf16x8 A1[8];
        A1[0] = cvt8(Sn0, Sn1);
        A1[1] = cvt8(Sn2, Sn3);
        A1[2] = cvt8(Sn4, Sn5);
        A1[3] = cvt8(Sn6, Sn7);
        A1[4] = cvt8(Se0, Se1);
        A1[5] = cvt8(Se2, Se3);
        A1[6] = cvt8(Se4, Se5);
        A1[7] = cvt8(Se6, Se7);

        // ---- issue NEXT tile's FULL gather burst (in flight all tile) ----
        {
            const float* sp = node + (size_t)nsidx * H_NODE + lk8 * 8;
            const float* dp = node + (size_t)ndidx * H_NODE + lk8 * 8;
            const float* ep = edgef + (size_t)nrowg * H_EDGE + lk8 * 8;
            Sn0 = *(const f32x4*)(sp);      Sn1 = *(const f32x4*)(sp + 4);
            Sn2 = *(const f32x4*)(sp + 32); Sn3 = *(const f32x4*)(sp + 36);
            Sn4 = *(const f32x4*)(dp);      Sn5 = *(const f32x4*)(dp + 4);
            Sn6 = *(const f32x4*)(dp + 32); Sn7 = *(const f32x4*)(dp + 36);
            Se0 = *(const f32x4*)(ep);      Se1 = *(const f32x4*)(ep + 4);
            Se2 = *(const f32x4*)(ep + 32); Se3 = *(const f32x4*)(ep + 36);
            Se4 = *(const f32x4*)(ep + 64); Se5 = *(const f32x4*)(ep + 68);
            Se6 = *(const f32x4*)(ep + 96); Se7 = *(const f32x4*)(ep + 100);
        }
        // ---- prefetch tile+2 indices ----
        int t2 = next + wstride;
        int t2rowg = t2 * 16 + lrow; if (t2rowg >= E) t2rowg = E - 1;
        int t2s = ei[t2rowg];
        int t2d = ei[E + t2rowg];

        // ---- GEMM1: [16x256] @ [256x128] ----
        f32x4 acc[8];
        #pragma unroll
        for (int n = 0; n < 8; ++n) acc[n] = (f32x4){0.f, 0.f, 0.f, 0.f};
        #pragma unroll
        for (int n = 0; n < 8; ++n) {
            const int col = n * 16 + lrow;
            const int cb  = col * 512;
            const int sw  = (col & 7) << 4;
            #pragma unroll
            for (int t = 0; t < 8; ++t) {
                int kb = t * 64 + lk8 * 16;
                bf16x8 bfrag = *(const bf16x8*)(lds + cb + (kb ^ sw));
                acc[n] = __builtin_amdgcn_mfma_f32_16x16x32_bf16(A1[t], bfrag, acc[n], 0, 0, 0);
            }
        }

        // ---- bias + relu -> h (bf16) to per-wave LDS (conflict-free swizzle) ----
        #pragma unroll
        for (int n = 0; n < 8; ++n) {
            const int g = n * 2 + (lrow >> 3);
            const int cl = (lrow & 7) * 2;
            #pragma unroll
            for (int i = 0; i < 4; ++i) {
                float u = fmaxf(acc[n][i] + bias1[n], 0.f);
                int row = lk8 * 4 + i;
                *(short*)(lds + hbase + tswz(row, g) + cl) = f2bf(u);
            }
        }
        // same-wave cross-lane LDS visibility: drain ds_writes before reads
        asm volatile("s_waitcnt lgkmcnt(0)" ::: "memory");

        // ---- GEMM2: [16x128] @ [128x128] ----
        bf16x8 A2[4];
        #pragma unroll
        for (int t = 0; t < 4; ++t)
            A2[t] = *(const bf16x8*)(lds + hbase + tswz(lrow, t * 4 + lk8));

        f32x4 acc2[8];
        #pragma unroll
        for (int n = 0; n < 8; ++n) acc2[n] = (f32x4){0.f, 0.f, 0.f, 0.f};
        #pragma unroll
        for (int n = 0; n < 8; ++n) {
            const int col = n * 16 + lrow;
            const int cb  = 65536 + col * 256;
            const int sw  = (col & 7) << 4;
            #pragma unroll
            for (int t = 0; t < 4; ++t) {
                int kb = t * 64 + lk8 * 16;
                bf16x8 bfrag = *(const bf16x8*)(lds + cb + (kb ^ sw));
                acc2[n] = __builtin_amdgcn_mfma_f32_16x16x32_bf16(A2[t], bfrag, acc2[n], 0, 0, 0);
            }
        }

        // ---- (b) residual reload in C-layout (L2-hot: rows fetched at tile top) ----
        float er[4][8];   // [i][n]: edgef[r0 + lk8*4 + i][n*16 + lrow]
        #pragma unroll
        for (int i = 0; i < 4; ++i) {
            int rr = r0 + lk8 * 4 + i; if (rr >= E) rr = E - 1;
            const float* ep = edgef + (size_t)rr * H_EDGE + lrow;
            #pragma unroll
            for (int n = 0; n < 8; ++n) er[i][n] = ep[n * 16];
        }

        // ---- bias2 + LayerNorm (C-layout) -> DIRECT f32 store + residual ----
        #pragma unroll
        for (int i = 0; i < 4; ++i) {
            float u[8];
            float s = 0.f, sq = 0.f;
            #pragma unroll
            for (int n = 0; n < 8; ++n) {
                u[n] = acc2[n][i] + bias2[n];
                s  += u[n];
                sq += u[n] * u[n];
            }
            #pragma unroll
            for (int m = 1; m < 16; m <<= 1) {
                s  += __shfl_xor(s,  m, 64);
                sq += __shfl_xor(sq, m, 64);
            }
            float mu  = s * (1.f / 128.f);
            float var = sq * (1.f / 128.f) - mu * mu;
            float rs  = rsqrtf(var + LN_EPS);
            int rr = r0 + lk8 * 4 + i;
            if (rr < E) {
                float* orow = out + (size_t)rr * H_EDGE + lrow;
                #pragma unroll
                for (int n = 0; n < 8; ++n) {
                    float w = (u[n] - mu) * rs * g8[n] + bt8[n] + er[i][n];
                    orow[n * 16] = w;
                }
            }
        }

        // ---- rotate pipeline state ----
        tile = next;  next = t2;
        nrowg = t2rowg; nsidx = t2s; ndidx = t2d;
    }
}

extern "C" void kernel_launch(void* const* d_in, const int* in_sizes, int n_in,
                              void* d_out, int out_size, void* d_ws, size_t ws_size,
                              hipStream_t stream) {
    const float* node  = (const float*)d_in[0];
    const float* edgef = (const float*)d_in[1];
    const int*   ei    = (const int*)d_in[2];    // int32 on device
    const float* W1    = (const float*)d_in[3];
    const float* b1    = (const float*)d_in[4];
    const float* W2    = (const float*)d_in[5];
    const float* b2    = (const float*)d_in[6];
    const float* gamma = (const float*)d_in[7];
    const float* beta  = (const float*)d_in[8];
    float* outp = (float*)d_out;
    const int E = in_sizes[2] / 2;   // edge_index is [2, E]

    hipLaunchKernelGGL(edge_update, dim3(GRID), dim3(BLOCK), 0, stream,
                       node, edgef, ei, W1, b1, W2, b2, gamma, beta, outp, E);
}